// Round 4
// baseline (1700.287 us; speedup 1.0000x reference)
//
#include <hip/hip_runtime.h>
#include <cstdint>

#define BATCH 4
#define DIMC 384
#define CINC 387
#define COMPC 64
#define GSZ 224

typedef __attribute__((ext_vector_type(8))) short bf16x8;
typedef __attribute__((ext_vector_type(4))) short s16x4;
typedef __attribute__((ext_vector_type(4))) float f32x4;

static __device__ __forceinline__ unsigned short f2bf(float x) {
  unsigned int u = __float_as_uint(x);
  unsigned int r = (u + 0x7fffu + ((u >> 16) & 1u)) >> 16;
  return (unsigned short)r;
}
static __device__ __forceinline__ float bf2f(unsigned short b) {
  return __uint_as_float(((unsigned int)b) << 16);
}
// split x into bf16 hi + bf16 lo (rne both; x ~= hi + lo)
static __device__ __forceinline__ void cvt2(float x, unsigned short& h, unsigned short& l) {
  unsigned int u = __float_as_uint(x);
  unsigned int hb = (u + 0x7fffu + ((u >> 16) & 1u)) >> 16;
  h = (unsigned short)hb;
  float r = x - __uint_as_float(hb << 16);
  unsigned int u2 = __float_as_uint(r);
  l = (unsigned short)((u2 + 0x7fffu + ((u2 >> 16) & 1u)) >> 16);
}

// ---------- antialiased bilinear resize, all 4 stages in one launch ----------
__global__ void resize_all(const float* __restrict__ g, float* __restrict__ o0,
                           float* __restrict__ o1, float* __restrict__ o2,
                           float* __restrict__ o3) {
  int s = blockIdx.y;
  int h = 14 << s;                  // 14, 28, 56, 112
  float* out = (s == 0) ? o0 : (s == 1) ? o1 : (s == 2) ? o2 : o3;
  int inv_scale = GSZ / h;
  int w = h;
  int idx = blockIdx.x * blockDim.x + threadIdx.x;
  int total = BATCH * 3 * h * w;
  if (idx >= total) return;
  int j = idx % w; int t = idx / w;
  int i = t % h; t /= h;
  float ks = (float)inv_scale;
  float sy = (i + 0.5f) * ks - 0.5f;
  float sx = (j + 0.5f) * ks - 0.5f;
  int y0 = (int)ceilf(sy - ks); if (y0 < 0) y0 = 0;
  int y1 = (int)floorf(sy + ks); if (y1 > GSZ - 1) y1 = GSZ - 1;
  int x0 = (int)ceilf(sx - ks); if (x0 < 0) x0 = 0;
  int x1 = (int)floorf(sx + ks); if (x1 > GSZ - 1) x1 = GSZ - 1;
  const float* gp = g + (size_t)t * GSZ * GSZ;
  float wsx = 0.f;
  for (int x = x0; x <= x1; ++x) wsx += fmaxf(0.f, 1.f - fabsf(sx - (float)x) / ks);
  float acc = 0.f, wsy = 0.f;
  for (int y = y0; y <= y1; ++y) {
    float wy = fmaxf(0.f, 1.f - fabsf(sy - (float)y) / ks);
    wsy += wy;
    if (wy > 0.f) {
      const float* rp = gp + (size_t)y * GSZ;
      float row = 0.f;
      for (int x = x0; x <= x1; ++x) {
        float wx = fmaxf(0.f, 1.f - fabsf(sx - (float)x) / ks);
        row += wx * rp[x];
      }
      acc += wy * row;
    }
  }
  out[idx] = acc / (wsx * wsy);
}

// ---------- weight prep ----------
__global__ void prep_cw(const float* __restrict__ c0, const float* __restrict__ c1,
                        const float* __restrict__ c2, const float* __restrict__ c3,
                        float* __restrict__ cwT) {
  int s = blockIdx.y;
  const float* cw = (s == 0) ? c0 : (s == 1) ? c1 : (s == 2) ? c2 : c3;
  int idx = blockIdx.x * 256 + threadIdx.x;
  if (idx >= CINC * COMPC) return;
  int ci = idx >> 6, co = idx & 63;
  cwT[s * (CINC * COMPC) + idx] = cw[co * CINC + ci];
}

// ewT2 layout: [s][pos][ci][tap][12]  (k padded 9->12 for float4 alignment)
#define EW2_PER_S (4 * COMPC * 9 * 12)
__global__ void prep_ew(const float* __restrict__ e0, const float* __restrict__ e1,
                        const float* __restrict__ e2, const float* __restrict__ e3,
                        float* __restrict__ ewT2) {
  int s = blockIdx.y;
  const float* ew = (s == 0) ? e0 : (s == 1) ? e1 : (s == 2) ? e2 : e3;
  int idx = blockIdx.x * 256 + threadIdx.x;
  if (idx >= EW2_PER_S) return;
  int k = idx % 12; int r = idx / 12;
  int tap = r % 9; r /= 9;
  int ci = r % COMPC; int pos = r / COMPC;
  float val = 0.f;
  if (k < 9) val = ew[(size_t)(k * 4 + pos) * (COMPC * 9) + ci * 9 + tap];
  ewT2[(size_t)s * EW2_PER_S + idx] = val;
}

#define KPAD 416
__global__ void prep_w(const float* __restrict__ pw, short* __restrict__ Whi,
                       short* __restrict__ Wlo) {
  int idx = blockIdx.x * 256 + threadIdx.x;
  if (idx >= DIMC * KPAD) return;
  int co = idx / KPAD, k = idx % KPAD;
  float v = (k < CINC) ? pw[co * CINC + k] : 0.f;
  unsigned short hb = f2bf(v);
  Whi[idx] = (short)hb;
  Wlo[idx] = (short)f2bf(v - bf2f(hb));
}

// ---------- 1x1 conv 387->64: thread = 1 px, 32 co; uniform s_load weights ----------
__global__ void comp_conv_kernel(const float* __restrict__ src, const float* __restrict__ g,
                                 const float* __restrict__ cwT, const float* __restrict__ cb,
                                 float* __restrict__ comp, int h, int w) {
  int hw = h * w;
  int p = blockIdx.x * 256 + threadIdx.x;
  if (p >= hw) return;
  int co0 = blockIdx.y * 32;
  int n = blockIdx.z;
  float acc[32];
  #pragma unroll
  for (int c = 0; c < 32; ++c) acc[c] = cb[co0 + c];
  const float* sp = src + (size_t)n * DIMC * hw + p;
  const float* wbase = cwT + co0;
  for (int ci = 0; ci < DIMC; ++ci) {
    float v = sp[(size_t)ci * hw];
    const float* wr = wbase + ci * COMPC;
    #pragma unroll
    for (int c = 0; c < 32; c += 4) {
      float4 wv = *(const float4*)(wr + c);
      acc[c] += wv.x * v; acc[c + 1] += wv.y * v;
      acc[c + 2] += wv.z * v; acc[c + 3] += wv.w * v;
    }
  }
  const float* gp = g + (size_t)n * 3 * hw + p;
  #pragma unroll
  for (int ci = 0; ci < 3; ++ci) {
    float v = gp[(size_t)ci * hw];
    const float* wr = wbase + (DIMC + ci) * COMPC;
    #pragma unroll
    for (int c = 0; c < 32; c += 4) {
      float4 wv = *(const float4*)(wr + c);
      acc[c] += wv.x * v; acc[c + 1] += wv.y * v;
      acc[c + 2] += wv.z * v; acc[c + 3] += wv.w * v;
    }
  }
  float* op = comp + (size_t)n * COMPC * hw + p;
  #pragma unroll
  for (int c = 0; c < 32; ++c) op[(size_t)(co0 + c) * hw] = acc[c];
}

// ---------- 3x3 conv 64->36 + pixel_shuffle + softmax: 2-px strips ----------
__global__ void enc_mask_kernel(const float* __restrict__ comp, const float* __restrict__ ewT2,
                                const float* __restrict__ eb, float* __restrict__ mask,
                                int h, int w) {
  int hw = h * w;
  int sw2 = w >> 1;
  int nstrip = h * sw2;
  int strip = blockIdx.x * 256 + threadIdx.x;
  if (strip >= nstrip) return;
  int pos = blockIdx.y;
  int n = blockIdx.z;
  int i = strip / sw2;
  int j0 = (strip - i * sw2) * 2;
  float acc[2][9];
  #pragma unroll
  for (int k = 0; k < 9; ++k) {
    float bv = eb[k * 4 + pos];
    acc[0][k] = bv; acc[1][k] = bv;
  }
  const float* cpn = comp + (size_t)n * COMPC * hw;
  const float* wpos = ewT2 + (size_t)pos * COMPC * 9 * 12;
  for (int ci = 0; ci < COMPC; ++ci) {
    const float* cp = cpn + (size_t)ci * hw;
    float v[3][4];
    #pragma unroll
    for (int di = 0; di < 3; ++di) {
      int y = i + di - 1;
      bool yok = (y >= 0 && y < h);
      #pragma unroll
      for (int xx = 0; xx < 4; ++xx) {
        int x = j0 - 1 + xx;
        v[di][xx] = (yok && x >= 0 && x < w) ? cp[(size_t)y * w + x] : 0.f;
      }
    }
    const float* wb = wpos + (size_t)ci * 9 * 12;
    #pragma unroll
    for (int tap = 0; tap < 9; ++tap) {
      int di = tap / 3, dj = tap % 3;
      float4 wa = *(const float4*)(wb + tap * 12);
      float4 wc = *(const float4*)(wb + tap * 12 + 4);
      float w8 = wb[tap * 12 + 8];
      #pragma unroll
      for (int px = 0; px < 2; ++px) {
        float val = v[di][dj + px];
        acc[px][0] += wa.x * val; acc[px][1] += wa.y * val;
        acc[px][2] += wa.z * val; acc[px][3] += wa.w * val;
        acc[px][4] += wc.x * val; acc[px][5] += wc.y * val;
        acc[px][6] += wc.z * val; acc[px][7] += wc.w * val;
        acc[px][8] += w8 * val;
      }
    }
  }
  int pp = pos >> 1, q = pos & 1;
  int H = 2 * h, W = 2 * w;
  #pragma unroll
  for (int px = 0; px < 2; ++px) {
    int jj = j0 + px;
    float m = -1e30f;
    #pragma unroll
    for (int k = 0; k < 9; ++k) m = fmaxf(m, acc[px][k]);
    float e[9]; float s = 0.f;
    #pragma unroll
    for (int k = 0; k < 9; ++k) { e[k] = __expf(acc[px][k] - m); s += e[k]; }
    float inv = 1.f / s;
    float* mp = mask + (((size_t)n * H + (2 * i + pp)) * W + (2 * jj + q)) * 9;
    #pragma unroll
    for (int k = 0; k < 9; ++k) mp[k] = e[k] * inv;
  }
}

// ---------- CARAFE reassembly (stages 1-3 only): 48 channels per block ----------
__global__ void carafe_kernel(const float* __restrict__ src, const float* __restrict__ mask,
                              float* __restrict__ out, int h, int w) {
  int p = blockIdx.x * blockDim.x + threadIdx.x;
  int hw = h * w;
  if (p >= hw) return;
  int c0 = blockIdx.y * 48, n = blockIdx.z;
  int i = p / w, j = p % w;
  int H = 2 * h, W = 2 * w;
  float m[4][9];
  #pragma unroll
  for (int pp = 0; pp < 2; ++pp)
    #pragma unroll
    for (int q = 0; q < 2; ++q) {
      const float* mp = mask + (((size_t)n * H + (2 * i + pp)) * W + (2 * j + q)) * 9;
      #pragma unroll
      for (int k = 0; k < 9; ++k) m[pp * 2 + q][k] = mp[k];
    }
  for (int cc = 0; cc < 48; ++cc) {
    int c = c0 + cc;
    const float* sp = src + ((size_t)(n * DIMC + c)) * hw;
    float v[9];
    #pragma unroll
    for (int k = 0; k < 9; ++k) {
      int y = i - 1 + k / 3, x = j - 1 + k % 3;
      v[k] = (y >= 0 && y < h && x >= 0 && x < w) ? sp[(size_t)y * w + x] : 0.f;
    }
    float* op = out + ((size_t)(n * DIMC + c)) * H * W;
    #pragma unroll
    for (int pp = 0; pp < 2; ++pp) {
      float a0 = 0.f, a1 = 0.f;
      #pragma unroll
      for (int k = 0; k < 9; ++k) {
        a0 += v[k] * m[pp * 2 + 0][k];
        a1 += v[k] * m[pp * 2 + 1][k];
      }
      float2 r; r.x = a0; r.y = a1;
      *(float2*)(op + (size_t)(2 * i + pp) * W + 2 * j) = r;
    }
  }
}

// ---------- FUSED carafe-stage4 + final 1x1 conv (bf16x3 MFMA) ----------
// Round-3 post-mortem: final_conv duration tracks hbm_bytes linearly at ~1650 GB/s
// (Little's-law traffic ceiling) -> delete the traffic. carafe4 wrote out (308MB),
// final re-read it (311MB): here carafe values are computed per 32-ch K-chunk from
// an LDS src window, converted to bf16 hi/lo fragments in LDS, and MFMA'd directly.
// Block: hr tile 32x4 (lowres 16x2), 1024 thr = 16 waves = 8 co-slices x 2 px-slices.
// LDS: X-frag dbuf 32KB + src dbuf 20.7KB = 53.5KB. acc 48 VGPR/thread.
__global__ __launch_bounds__(1024, 4) void fused_carafe_final(
    const float* __restrict__ s8, const float* __restrict__ mask,
    const float* __restrict__ guid, const short* __restrict__ Whi,
    const short* __restrict__ Wlo, const float* __restrict__ pb,
    float* __restrict__ out) {
  __shared__ __align__(16) short XH[2][4096];
  __shared__ __align__(16) short XL[2][4096];
  __shared__ __align__(16) float SB[2][2592];   // [row4][col18][ch pad36]

  const int HW = GSZ * GSZ;
  const int n = blockIdx.y;
  const int tx = blockIdx.x % 7, ty = blockIdx.x / 7;
  const int lj0 = tx * 16, li0 = ty * 2;        // lowres tile origin
  const int Jh0 = tx * 32, Ih0 = ty * 4;        // highres tile origin
  const int tid = threadIdx.x;
  const int lane = tid & 63;
  const int wv = tid >> 6;
  const int lm = lane & 15, qq = lane >> 4;
  const int co_sl = wv >> 1, px_sl = wv & 1;

  // carafe-producer mapping: thread = (k-quad kq, hr px P)
  const int P = tid & 127;
  const int kq = tid >> 7;                      // 0..7
  const int I_loc = P >> 5, J_loc = P & 31;
  const int i_loc = I_loc >> 1, j_loc = J_loc >> 1;
  const int xaddr = (((P >> 4) * 4 + (kq >> 1)) * 16 + (P & 15)) * 8 + (kq & 1) * 4;

  // masks for this thread's hr px (invariant over kt)
  float m9[9];
  {
    const float* mp = mask + (((size_t)n * GSZ + (Ih0 + I_loc)) * GSZ + (Jh0 + J_loc)) * 9;
    #pragma unroll
    for (int k = 0; k < 9; ++k) m9[k] = mp[k];
  }
  // guidance values for chunk 12 (k=384..386)
  float gv[3] = {0.f, 0.f, 0.f};
  if (kq == 0) {
    #pragma unroll
    for (int g = 0; g < 3; ++g)
      gv[g] = guid[((size_t)(n * 3 + g) * GSZ + (Ih0 + I_loc)) * GSZ + (Jh0 + J_loc)];
  }

  const float* s8n = s8 + (size_t)n * DIMC * 112 * 112;

  // precomputed staging indices (3 strided slots per thread, invariant over kt)
  int g_off[3], sb_off[3];
  bool inr[3], img[3];
  #pragma unroll
  for (int r = 0; r < 3; ++r) {
    int idx = tid + (r << 10);
    inr[r] = idx < 2304;
    int idc = inr[r] ? idx : 0;
    int seg = idc / 18, col = idc - seg * 18;
    int ch = seg >> 2, row = seg & 3;
    int y = li0 - 1 + row, x = lj0 - 1 + col;
    img[r] = (y >= 0 && y < 112 && x >= 0 && x < 112);
    g_off[r] = (ch * 112 + (img[r] ? y : 0)) * 112 + (img[r] ? x : 0);
    sb_off[r] = (row * 18 + col) * 36 + ch;
  }

  f32x4 acc[3][4];
  #pragma unroll
  for (int mt = 0; mt < 3; ++mt)
    #pragma unroll
    for (int nt = 0; nt < 4; ++nt) acc[mt][nt] = (f32x4){0.f, 0.f, 0.f, 0.f};

  // carafe producer for one 32-ch chunk: SB[bb] -> XH/XL[bb]
  auto carafe_produce = [&](int bb) {
    float a0 = 0.f, a1 = 0.f, a2 = 0.f, a3 = 0.f;
    #pragma unroll
    for (int tap = 0; tap < 9; ++tap) {
      int di = tap / 3, dj = tap % 3;
      float4 s4 = *(const float4*)&SB[bb][((i_loc + di) * 18 + (j_loc + dj)) * 36 + kq * 4];
      a0 += s4.x * m9[tap];
      a1 += s4.y * m9[tap];
      a2 += s4.z * m9[tap];
      a3 += s4.w * m9[tap];
    }
    unsigned short h0, l0, h1, l1, h2, l2, h3, l3;
    cvt2(a0, h0, l0); cvt2(a1, h1, l1); cvt2(a2, h2, l2); cvt2(a3, h3, l3);
    *(s16x4*)&XH[bb][xaddr] = (s16x4){(short)h0, (short)h1, (short)h2, (short)h3};
    *(s16x4*)&XL[bb][xaddr] = (s16x4){(short)l0, (short)l1, (short)l2, (short)l3};
  };

  // ---- prologue: stage src chunk 0 -> SB[0] ----
  {
    float v[3];
    #pragma unroll
    for (int r = 0; r < 3; ++r)
      v[r] = (inr[r] && img[r]) ? s8n[g_off[r]] : 0.f;
    #pragma unroll
    for (int r = 0; r < 3; ++r)
      if (inr[r]) SB[0][sb_off[r]] = v[r];
  }
  __syncthreads();
  // ---- carafe chunk 0 -> Xbuf[0]; stage src chunk 1 -> SB[1] ----
  {
    float v[3];
    const float* sc = s8n + (size_t)32 * 112 * 112;
    #pragma unroll
    for (int r = 0; r < 3; ++r)
      v[r] = (inr[r] && img[r]) ? sc[g_off[r]] : 0.f;
    carafe_produce(0);
    #pragma unroll
    for (int r = 0; r < 3; ++r)
      if (inr[r]) SB[1][sb_off[r]] = v[r];
  }
  __syncthreads();

  // ---- main loop ----
  #pragma unroll 1
  for (int kt = 0; kt < 13; ++kt) {
    const int cur = kt & 1;
    // weights for this chunk (L2; latency hidden under carafe VALU below)
    bf16x8 ah[3], al[3];
    #pragma unroll
    for (int mt = 0; mt < 3; ++mt) {
      int co = co_sl * 48 + mt * 16 + lm;
      size_t woff = (size_t)co * KPAD + kt * 32 + qq * 8;
      ah[mt] = *(const bf16x8*)(Whi + woff);
      al[mt] = *(const bf16x8*)(Wlo + woff);
    }
    // issue src loads for chunk kt+2 (consumed at end of this iteration)
    float sv[3] = {0.f, 0.f, 0.f};
    if (kt <= 9) {
      const float* sc = s8n + (size_t)(kt + 2) * 32 * 112 * 112;
      #pragma unroll
      for (int r = 0; r < 3; ++r)
        if (inr[r] && img[r]) sv[r] = sc[g_off[r]];
    }
    // produce X chunk kt+1
    if (kt <= 10) {
      carafe_produce(cur ^ 1);
    } else if (kt == 11) {
      // guidance chunk (k=384..386) + zero pad -> Xbuf[0]
      float a0 = gv[0], a1 = gv[1], a2 = gv[2];
      unsigned short h0, l0, h1, l1, h2, l2;
      cvt2(a0, h0, l0); cvt2(a1, h1, l1); cvt2(a2, h2, l2);
      if (kq != 0) { h0 = l0 = h1 = l1 = h2 = l2 = 0; }
      *(s16x4*)&XH[0][xaddr] = (s16x4){(short)h0, (short)h1, (short)h2, 0};
      *(s16x4*)&XL[0][xaddr] = (s16x4){(short)l0, (short)l1, (short)l2, 0};
    }
    // MFMA chunk kt
    #pragma unroll
    for (int nt = 0; nt < 4; ++nt) {
      int a = (((px_sl * 4 + nt) * 4 + qq) * 16 + lm) * 8;
      bf16x8 bh = *(const bf16x8*)&XH[cur][a];
      bf16x8 bl = *(const bf16x8*)&XL[cur][a];
      #pragma unroll
      for (int mt = 0; mt < 3; ++mt) {
        acc[mt][nt] = __builtin_amdgcn_mfma_f32_16x16x32_bf16(ah[mt], bh, acc[mt][nt], 0, 0, 0);
        acc[mt][nt] = __builtin_amdgcn_mfma_f32_16x16x32_bf16(ah[mt], bl, acc[mt][nt], 0, 0, 0);
        acc[mt][nt] = __builtin_amdgcn_mfma_f32_16x16x32_bf16(al[mt], bh, acc[mt][nt], 0, 0, 0);
      }
    }
    // write staged src chunk kt+2 -> SB[cur]
    if (kt <= 9) {
      #pragma unroll
      for (int r = 0; r < 3; ++r)
        if (inr[r]) SB[cur][sb_off[r]] = sv[r];
    }
    if (kt < 12) __syncthreads();
  }

  // ---- epilogue: C[co, px] ----
  #pragma unroll
  for (int mt = 0; mt < 3; ++mt) {
    #pragma unroll
    for (int nt = 0; nt < 4; ++nt) {
      #pragma unroll
      for (int r = 0; r < 4; ++r) {
        int co = co_sl * 48 + mt * 16 + qq * 4 + r;
        int px = px_sl * 64 + nt * 16 + lm;
        int I = Ih0 + (px >> 5), J = Jh0 + (px & 31);
        out[((size_t)(n * DIMC + co)) * HW + (size_t)I * GSZ + J] = acc[mt][nt][r] + pb[co];
      }
    }
  }
}

extern "C" void kernel_launch(void* const* d_in, const int* in_sizes, int n_in,
                              void* d_out, int out_size, void* d_ws, size_t ws_size,
                              hipStream_t stream) {
  const float* source   = (const float*)d_in[0];
  const float* guidance = (const float*)d_in[1];
  const float* cw[4] = {(const float*)d_in[2],  (const float*)d_in[6],
                        (const float*)d_in[10], (const float*)d_in[14]};
  const float* cb[4] = {(const float*)d_in[3],  (const float*)d_in[7],
                        (const float*)d_in[11], (const float*)d_in[15]};
  const float* ew[4] = {(const float*)d_in[4],  (const float*)d_in[8],
                        (const float*)d_in[12], (const float*)d_in[16]};
  const float* eb[4] = {(const float*)d_in[5],  (const float*)d_in[9],
                        (const float*)d_in[13], (const float*)d_in[17]};
  const float* pw = (const float*)d_in[18];
  const float* pb = (const float*)d_in[19];
  float* out = (float*)d_out;

  float* ws = (float*)d_ws;
  float* g14  = ws;                         // 4*3*14*14   = 2352
  float* g28  = g14 + 2352;                 // 4*3*28*28   = 9408
  float* g56  = g28 + 9408;                 // 4*3*56*56   = 37632
  float* g112 = g56 + 37632;                // 4*3*112*112 = 150528
  float* comp_buf = g112 + 150528;          // 4*64*112*112  = 3211264
  float* mask_buf = comp_buf + 3211264;     // 4*224*224*9   = 1806336
  float* s2  = mask_buf + 1806336;          // 4*384*28*28   = 1204224
  float* s4  = s2 + 1204224;                // 4*384*56*56   = 4816896
  float* s8  = s4 + 4816896;                // 4*384*112*112 = 19267584
  float* cwT = s8 + 19267584;               // 4*387*64      = 99072
  float* ewT2 = cwT + 99072;                // 4*27648       = 110592
  short* Whi = (short*)(ewT2 + 110592);     // 384*416 shorts
  short* Wlo = Whi + DIMC * KPAD;

  prep_cw<<<dim3((CINC * COMPC + 255) / 256, 4), 256, 0, stream>>>(cw[0], cw[1], cw[2], cw[3], cwT);
  prep_ew<<<dim3((EW2_PER_S + 255) / 256, 4), 256, 0, stream>>>(ew[0], ew[1], ew[2], ew[3], ewT2);
  prep_w<<<(DIMC * KPAD + 255) / 256, 256, 0, stream>>>(pw, Whi, Wlo);
  resize_all<<<dim3((BATCH * 3 * 112 * 112 + 255) / 256, 4), 256, 0, stream>>>(
      guidance, g14, g28, g56, g112);

  const float* srcs[4] = {source, s2, s4, s8};
  float* outs[4] = {s2, s4, s8, out};
  float* gbufs[4] = {g14, g28, g56, g112};
  const int hs[4] = {14, 28, 56, 112};
  for (int s = 0; s < 4; ++s) {
    int h = hs[s], w = h, hw = h * w;
    int sw2 = w / 2;
    comp_conv_kernel<<<dim3((hw + 255) / 256, 2, BATCH), 256, 0, stream>>>(
        srcs[s], gbufs[s], cwT + s * (CINC * COMPC), cb[s], comp_buf, h, w);
    enc_mask_kernel<<<dim3((h * sw2 + 255) / 256, 4, BATCH), 256, 0, stream>>>(
        comp_buf, ewT2 + (size_t)s * EW2_PER_S, eb[s], mask_buf, h, w);
    if (s < 3)
      carafe_kernel<<<dim3((hw + 255) / 256, DIMC / 48, BATCH), 256, 0, stream>>>(
          srcs[s], mask_buf, outs[s], h, w);
  }
  fused_carafe_final<<<dim3(392, BATCH), 1024, 0, stream>>>(
      s8, mask_buf, guidance, Whi, Wlo, pb, out);
}

// Round 5
// 1424.812 us; speedup vs baseline: 1.1933x; 1.1933x over previous
//
#include <hip/hip_runtime.h>
#include <cstdint>

#define BATCH 4
#define DIMC 384
#define CINC 387
#define COMPC 64
#define GSZ 224

typedef __attribute__((ext_vector_type(8))) short bf16x8;
typedef __attribute__((ext_vector_type(4))) short s16x4;
typedef __attribute__((ext_vector_type(4))) float f32x4;

static __device__ __forceinline__ unsigned short f2bf(float x) {
  unsigned int u = __float_as_uint(x);
  unsigned int r = (u + 0x7fffu + ((u >> 16) & 1u)) >> 16;
  return (unsigned short)r;
}
static __device__ __forceinline__ float bf2f(unsigned short b) {
  return __uint_as_float(((unsigned int)b) << 16);
}
static __device__ __forceinline__ void cvt2(float x, unsigned short& h, unsigned short& l) {
  unsigned int u = __float_as_uint(x);
  unsigned int hb = (u + 0x7fffu + ((u >> 16) & 1u)) >> 16;
  h = (unsigned short)hb;
  float r = x - __uint_as_float(hb << 16);
  unsigned int u2 = __float_as_uint(r);
  l = (unsigned short)((u2 + 0x7fffu + ((u2 >> 16) & 1u)) >> 16);
}

#define KPAD 416
#define EW2_PER_S (4 * COMPC * 9 * 12)

// ---------- one launch: prep_cw + prep_ew + prep_w + 4-stage resize ----------
__global__ void prep_all(const float* __restrict__ c0, const float* __restrict__ c1,
                         const float* __restrict__ c2, const float* __restrict__ c3,
                         const float* __restrict__ e0, const float* __restrict__ e1,
                         const float* __restrict__ e2, const float* __restrict__ e3,
                         const float* __restrict__ pw,
                         float* __restrict__ cwT, float* __restrict__ ewT2,
                         short* __restrict__ Whi, short* __restrict__ Wlo,
                         const float* __restrict__ g,
                         float* __restrict__ r0, float* __restrict__ r1,
                         float* __restrict__ r2, float* __restrict__ r3) {
  int type = blockIdx.y;
  int idx = blockIdx.x * 256 + threadIdx.x;
  if (type == 0) {                      // cwT: [s][ci][co], 4*24768
    if (idx >= 4 * CINC * COMPC) return;
    int s = idx / (CINC * COMPC), r = idx % (CINC * COMPC);
    const float* cw = (s == 0) ? c0 : (s == 1) ? c1 : (s == 2) ? c2 : c3;
    int ci = r >> 6, co = r & 63;
    cwT[idx] = cw[co * CINC + ci];
  } else if (type == 1) {               // ewT2: [s][pos][ci][tap][12], 4*27648
    if (idx >= 4 * EW2_PER_S) return;
    int s = idx / EW2_PER_S, r = idx % EW2_PER_S;
    const float* ew = (s == 0) ? e0 : (s == 1) ? e1 : (s == 2) ? e2 : e3;
    int k = r % 12; int rr = r / 12;
    int tap = rr % 9; rr /= 9;
    int ci = rr % COMPC; int pos = rr / COMPC;
    float val = 0.f;
    if (k < 9) val = ew[(size_t)(k * 4 + pos) * (COMPC * 9) + ci * 9 + tap];
    ewT2[idx] = val;
  } else if (type == 2) {               // Whi/Wlo: 384*416
    if (idx >= DIMC * KPAD) return;
    int co = idx / KPAD, k = idx % KPAD;
    float v = (k < CINC) ? pw[co * CINC + k] : 0.f;
    unsigned short hb = f2bf(v);
    Whi[idx] = (short)hb;
    Wlo[idx] = (short)f2bf(v - bf2f(hb));
  } else {                              // antialiased resize, 4 stages flat
    int s, base;
    if (idx < 2352)        { s = 0; base = 0; }
    else if (idx < 11760)  { s = 1; base = 2352; }
    else if (idx < 49392)  { s = 2; base = 11760; }
    else if (idx < 199920) { s = 3; base = 49392; }
    else return;
    int h = 14 << s, w = h;
    float* out = (s == 0) ? r0 : (s == 1) ? r1 : (s == 2) ? r2 : r3;
    int inv_scale = GSZ / h;
    int local = idx - base;
    int j = local % w; int t = local / w;
    int i = t % h; t /= h;
    float ks = (float)inv_scale;
    float sy = (i + 0.5f) * ks - 0.5f;
    float sx = (j + 0.5f) * ks - 0.5f;
    int y0 = (int)ceilf(sy - ks); if (y0 < 0) y0 = 0;
    int y1 = (int)floorf(sy + ks); if (y1 > GSZ - 1) y1 = GSZ - 1;
    int x0 = (int)ceilf(sx - ks); if (x0 < 0) x0 = 0;
    int x1 = (int)floorf(sx + ks); if (x1 > GSZ - 1) x1 = GSZ - 1;
    const float* gp = g + (size_t)t * GSZ * GSZ;
    float wsx = 0.f;
    for (int x = x0; x <= x1; ++x) wsx += fmaxf(0.f, 1.f - fabsf(sx - (float)x) / ks);
    float acc = 0.f, wsy = 0.f;
    for (int y = y0; y <= y1; ++y) {
      float wy = fmaxf(0.f, 1.f - fabsf(sy - (float)y) / ks);
      wsy += wy;
      if (wy > 0.f) {
        const float* rp = gp + (size_t)y * GSZ;
        float row = 0.f;
        for (int x = x0; x <= x1; ++x) {
          float wx = fmaxf(0.f, 1.f - fabsf(sx - (float)x) / ks);
          row += wx * rp[x];
        }
        acc += wy * row;
      }
    }
    out[local] = acc / (wsx * wsy);
  }
}

// ---------- 1x1 conv 387->64: thread = 1 px, 32 co; weights staged in LDS ----------
template <int H>
__global__ void comp_conv_kernel(const float* __restrict__ src, const float* __restrict__ g,
                                 const float* __restrict__ cwT, const float* __restrict__ cb,
                                 float* __restrict__ comp) {
  constexpr int hw = H * H;
  __shared__ __align__(16) float WL[CINC * 32];     // 49.5 KB co-half slice
  int co0 = blockIdx.y * 32;
  for (int idx = threadIdx.x; idx < CINC * 32; idx += 256) {
    int ci = idx >> 5, c = idx & 31;
    WL[idx] = cwT[ci * COMPC + co0 + c];
  }
  __syncthreads();
  int p = blockIdx.x * 256 + threadIdx.x;
  if (p >= hw) return;
  int n = blockIdx.z;
  float acc[32];
  #pragma unroll
  for (int c = 0; c < 32; ++c) acc[c] = cb[co0 + c];
  const float* sp = src + (size_t)n * DIMC * hw + p;
  for (int ci = 0; ci < DIMC; ++ci) {
    float v = sp[(size_t)ci * hw];
    const float* wr = &WL[ci * 32];
    #pragma unroll
    for (int c = 0; c < 32; c += 4) {
      float4 wv = *(const float4*)(wr + c);
      acc[c] += wv.x * v; acc[c + 1] += wv.y * v;
      acc[c + 2] += wv.z * v; acc[c + 3] += wv.w * v;
    }
  }
  const float* gp = g + (size_t)n * 3 * hw + p;
  #pragma unroll
  for (int ci = 0; ci < 3; ++ci) {
    float v = gp[(size_t)ci * hw];
    const float* wr = &WL[(DIMC + ci) * 32];
    #pragma unroll
    for (int c = 0; c < 32; c += 4) {
      float4 wv = *(const float4*)(wr + c);
      acc[c] += wv.x * v; acc[c + 1] += wv.y * v;
      acc[c + 2] += wv.z * v; acc[c + 3] += wv.w * v;
    }
  }
  float* op = comp + (size_t)n * COMPC * hw + p;
  #pragma unroll
  for (int c = 0; c < 32; ++c) op[(size_t)(co0 + c) * hw] = acc[c];
}

// ---------- 3x3 conv 64->36 + pixel_shuffle + softmax: weights staged in LDS ----------
template <int H>
__global__ void enc_mask_kernel(const float* __restrict__ comp, const float* __restrict__ ewT2,
                                const float* __restrict__ eb, float* __restrict__ mask) {
  constexpr int hw = H * H;
  constexpr int sw2 = H / 2;
  constexpr int nstrip = H * sw2;
  __shared__ __align__(16) float WL[COMPC * 9 * 12];   // 27.6 KB pos slice
  {
    const float* wpos = ewT2 + (size_t)blockIdx.y * (COMPC * 9 * 12);
    for (int idx = threadIdx.x; idx < COMPC * 9 * 12; idx += 256) WL[idx] = wpos[idx];
  }
  __syncthreads();
  int strip = blockIdx.x * 256 + threadIdx.x;
  if (strip >= nstrip) return;
  int pos = blockIdx.y;
  int n = blockIdx.z;
  int i = strip / sw2;
  int j0 = (strip - i * sw2) * 2;
  float acc[2][9];
  #pragma unroll
  for (int k = 0; k < 9; ++k) {
    float bv = eb[k * 4 + pos];
    acc[0][k] = bv; acc[1][k] = bv;
  }
  const float* cpn = comp + (size_t)n * COMPC * hw;
  for (int ci = 0; ci < COMPC; ++ci) {
    const float* cp = cpn + (size_t)ci * hw;
    float v[3][4];
    #pragma unroll
    for (int di = 0; di < 3; ++di) {
      int y = i + di - 1;
      bool yok = (y >= 0 && y < H);
      #pragma unroll
      for (int xx = 0; xx < 4; ++xx) {
        int x = j0 - 1 + xx;
        v[di][xx] = (yok && x >= 0 && x < H) ? cp[(size_t)y * H + x] : 0.f;
      }
    }
    const float* wb = &WL[ci * 108];
    #pragma unroll
    for (int tap = 0; tap < 9; ++tap) {
      int di = tap / 3, dj = tap % 3;
      float4 wa = *(const float4*)(wb + tap * 12);
      float4 wc = *(const float4*)(wb + tap * 12 + 4);
      float w8 = wb[tap * 12 + 8];
      #pragma unroll
      for (int px = 0; px < 2; ++px) {
        float val = v[di][dj + px];
        acc[px][0] += wa.x * val; acc[px][1] += wa.y * val;
        acc[px][2] += wa.z * val; acc[px][3] += wa.w * val;
        acc[px][4] += wc.x * val; acc[px][5] += wc.y * val;
        acc[px][6] += wc.z * val; acc[px][7] += wc.w * val;
        acc[px][8] += w8 * val;
      }
    }
  }
  int pp = pos >> 1, q = pos & 1;
  constexpr int W = 2 * H;
  #pragma unroll
  for (int px = 0; px < 2; ++px) {
    int jj = j0 + px;
    float m = -1e30f;
    #pragma unroll
    for (int k = 0; k < 9; ++k) m = fmaxf(m, acc[px][k]);
    float e[9]; float s = 0.f;
    #pragma unroll
    for (int k = 0; k < 9; ++k) { e[k] = __expf(acc[px][k] - m); s += e[k]; }
    float inv = 1.f / s;
    float* mp = mask + (((size_t)n * W + (2 * i + pp)) * W + (2 * jj + q)) * 9;
    #pragma unroll
    for (int k = 0; k < 9; ++k) mp[k] = e[k] * inv;
  }
}

// ---------- CARAFE reassembly: 48 channels per block ----------
template <int H>
__global__ void carafe_kernel(const float* __restrict__ src, const float* __restrict__ mask,
                              float* __restrict__ out) {
  constexpr int hw = H * H;
  constexpr int W = 2 * H;
  int p = blockIdx.x * blockDim.x + threadIdx.x;
  if (p >= hw) return;
  int c0 = blockIdx.y * 48, n = blockIdx.z;
  int i = p / H, j = p % H;
  float m[4][9];
  #pragma unroll
  for (int pp = 0; pp < 2; ++pp)
    #pragma unroll
    for (int q = 0; q < 2; ++q) {
      const float* mp = mask + (((size_t)n * W + (2 * i + pp)) * W + (2 * j + q)) * 9;
      #pragma unroll
      for (int k = 0; k < 9; ++k) m[pp * 2 + q][k] = mp[k];
    }
  for (int cc = 0; cc < 48; ++cc) {
    int c = c0 + cc;
    const float* sp = src + ((size_t)(n * DIMC + c)) * hw;
    float v[9];
    #pragma unroll
    for (int k = 0; k < 9; ++k) {
      int y = i - 1 + k / 3, x = j - 1 + k % 3;
      v[k] = (y >= 0 && y < H && x >= 0 && x < H) ? sp[(size_t)y * H + x] : 0.f;
    }
    float* op = out + ((size_t)(n * DIMC + c)) * W * W;
    #pragma unroll
    for (int pp = 0; pp < 2; ++pp) {
      float a0 = 0.f, a1 = 0.f;
      #pragma unroll
      for (int k = 0; k < 9; ++k) {
        a0 += v[k] * m[pp * 2 + 0][k];
        a1 += v[k] * m[pp * 2 + 1][k];
      }
      float2 r; r.x = a0; r.y = a1;
      *(float2*)(op + (size_t)(2 * i + pp) * W + 2 * j) = r;
    }
  }
}

// ---------- final 1x1 conv 387->384 via bf16x3 MFMA (round-2 v3, measured 302us) ----------
__global__ __launch_bounds__(512, 4) void final_conv_mfma3(
    const float* __restrict__ guid, const short* __restrict__ Whi,
    const short* __restrict__ Wlo, const float* __restrict__ pb,
    float* __restrict__ out) {
  __shared__ short XH[2][2048];
  __shared__ short XL[2][2048];
  const int HW = GSZ * GSZ;
  const int n = blockIdx.y;
  const int px0 = blockIdx.x * 64;
  const int tid = threadIdx.x;
  const int wv = tid >> 6;
  const int lane = tid & 63;
  const int lm = lane & 15, qq = lane >> 4;

  const int s_nt = lane >> 4, s_lm = lane & 15;
  const int s_qq = wv >> 1;
  const int s_jh = (wv & 1) * 4;
  const int waddr = ((s_nt * 4 + s_qq) * 16 + s_lm) * 8 + s_jh;

  const float* Xb = out + (size_t)n * DIMC * HW + px0 + lane;
  const float* Gb = guid + (size_t)n * 3 * HW + px0 + lane;

  f32x4 acc[3][4];
  #pragma unroll
  for (int mt = 0; mt < 3; ++mt)
    #pragma unroll
    for (int nt = 0; nt < 4; ++nt) acc[mt][nt] = (f32x4){0.f, 0.f, 0.f, 0.f};

  float nvA[4];
  {
    unsigned short hs[4], ls[4];
    #pragma unroll
    for (int i = 0; i < 4; ++i) {
      float v = Xb[(size_t)(wv * 4 + i) * HW];
      cvt2(v, hs[i], ls[i]);
    }
    *(s16x4*)&XH[0][waddr] = (s16x4){(short)hs[0], (short)hs[1], (short)hs[2], (short)hs[3]};
    *(s16x4*)&XL[0][waddr] = (s16x4){(short)ls[0], (short)ls[1], (short)ls[2], (short)ls[3]};
    #pragma unroll
    for (int i = 0; i < 4; ++i) nvA[i] = Xb[(size_t)(32 + wv * 4 + i) * HW];
  }
  __syncthreads();

  for (int kt = 0; kt < 13; ++kt) {
    const int cur = kt & 1;
    bf16x8 bh[4], bl[4];
    #pragma unroll
    for (int nt = 0; nt < 4; ++nt) {
      int a = ((nt * 4 + qq) * 16 + lm) * 8;
      bh[nt] = *(const bf16x8*)&XH[cur][a];
      bl[nt] = *(const bf16x8*)&XL[cur][a];
    }
    #pragma unroll
    for (int mt = 0; mt < 3; ++mt) {
      int co = wv * 48 + mt * 16 + lm;
      size_t woff = (size_t)co * KPAD + kt * 32 + qq * 8;
      bf16x8 ah = *(const bf16x8*)(Whi + woff);
      bf16x8 al = *(const bf16x8*)(Wlo + woff);
      #pragma unroll
      for (int nt = 0; nt < 4; ++nt) {
        acc[mt][nt] = __builtin_amdgcn_mfma_f32_16x16x32_bf16(ah, bh[nt], acc[mt][nt], 0, 0, 0);
        acc[mt][nt] = __builtin_amdgcn_mfma_f32_16x16x32_bf16(ah, bl[nt], acc[mt][nt], 0, 0, 0);
        acc[mt][nt] = __builtin_amdgcn_mfma_f32_16x16x32_bf16(al, bh[nt], acc[mt][nt], 0, 0, 0);
      }
    }
    __builtin_amdgcn_sched_barrier(0);
    float nvB[4] = {0.f, 0.f, 0.f, 0.f};
    if (kt <= 10) {
      int kb = (kt + 2) * 32 + wv * 4;
      if (kt < 10) {
        #pragma unroll
        for (int i = 0; i < 4; ++i) nvB[i] = Xb[(size_t)(kb + i) * HW];
      } else {
        #pragma unroll
        for (int i = 0; i < 4; ++i) {
          int k = kb + i;
          nvB[i] = (k < CINC) ? Gb[(size_t)(k - DIMC) * HW] : 0.f;
        }
      }
    }
    if (kt <= 11) {
      unsigned short hs[4], ls[4];
      #pragma unroll
      for (int i = 0; i < 4; ++i) cvt2(nvA[i], hs[i], ls[i]);
      *(s16x4*)&XH[cur ^ 1][waddr] = (s16x4){(short)hs[0], (short)hs[1], (short)hs[2], (short)hs[3]};
      *(s16x4*)&XL[cur ^ 1][waddr] = (s16x4){(short)ls[0], (short)ls[1], (short)ls[2], (short)ls[3]};
    }
    __syncthreads();
    #pragma unroll
    for (int i = 0; i < 4; ++i) nvA[i] = nvB[i];
  }

  #pragma unroll
  for (int mt = 0; mt < 3; ++mt) {
    #pragma unroll
    for (int nt = 0; nt < 4; ++nt) {
      #pragma unroll
      for (int r = 0; r < 4; ++r) {
        int co = wv * 48 + mt * 16 + qq * 4 + r;
        int px = px0 + nt * 16 + lm;
        out[((size_t)(n * DIMC + co)) * HW + px] = acc[mt][nt][r] + pb[co];
      }
    }
  }
}

extern "C" void kernel_launch(void* const* d_in, const int* in_sizes, int n_in,
                              void* d_out, int out_size, void* d_ws, size_t ws_size,
                              hipStream_t stream) {
  const float* source   = (const float*)d_in[0];
  const float* guidance = (const float*)d_in[1];
  const float* cw[4] = {(const float*)d_in[2],  (const float*)d_in[6],
                        (const float*)d_in[10], (const float*)d_in[14]};
  const float* cb[4] = {(const float*)d_in[3],  (const float*)d_in[7],
                        (const float*)d_in[11], (const float*)d_in[15]};
  const float* ew[4] = {(const float*)d_in[4],  (const float*)d_in[8],
                        (const float*)d_in[12], (const float*)d_in[16]};
  const float* eb[4] = {(const float*)d_in[5],  (const float*)d_in[9],
                        (const float*)d_in[13], (const float*)d_in[17]};
  const float* pw = (const float*)d_in[18];
  const float* pb = (const float*)d_in[19];
  float* out = (float*)d_out;

  float* ws = (float*)d_ws;
  float* g14  = ws;                         // 4*3*14*14   = 2352
  float* g28  = g14 + 2352;                 // 4*3*28*28   = 9408
  float* g56  = g28 + 9408;                 // 4*3*56*56   = 37632
  float* g112 = g56 + 37632;                // 4*3*112*112 = 150528
  float* comp_buf = g112 + 150528;          // 4*64*112*112  = 3211264
  float* mask_buf = comp_buf + 3211264;     // 4*224*224*9   = 1806336
  float* s2  = mask_buf + 1806336;          // 4*384*28*28   = 1204224
  float* s4  = s2 + 1204224;                // 4*384*56*56   = 4816896
  float* s8  = s4 + 4816896;                // 4*384*112*112 = 19267584
  float* cwT = s8 + 19267584;               // 4*387*64      = 99072
  float* ewT2 = cwT + 99072;                // 4*27648       = 110592
  short* Whi = (short*)(ewT2 + 110592);     // 384*416 shorts
  short* Wlo = Whi + DIMC * KPAD;

  prep_all<<<dim3(782, 4), 256, 0, stream>>>(
      cw[0], cw[1], cw[2], cw[3], ew[0], ew[1], ew[2], ew[3], pw,
      cwT, ewT2, Whi, Wlo, guidance, g14, g28, g56, g112);

  // stage 0: 14 -> 28
  comp_conv_kernel<14><<<dim3(1, 2, BATCH), 256, 0, stream>>>(
      source, g14, cwT + 0 * (CINC * COMPC), cb[0], comp_buf);
  enc_mask_kernel<14><<<dim3(1, 4, BATCH), 256, 0, stream>>>(
      comp_buf, ewT2 + 0 * (size_t)EW2_PER_S, eb[0], mask_buf);
  carafe_kernel<14><<<dim3(1, DIMC / 48, BATCH), 256, 0, stream>>>(
      source, mask_buf, s2);
  // stage 1: 28 -> 56
  comp_conv_kernel<28><<<dim3(4, 2, BATCH), 256, 0, stream>>>(
      s2, g28, cwT + 1 * (CINC * COMPC), cb[1], comp_buf);
  enc_mask_kernel<28><<<dim3(2, 4, BATCH), 256, 0, stream>>>(
      comp_buf, ewT2 + 1 * (size_t)EW2_PER_S, eb[1], mask_buf);
  carafe_kernel<28><<<dim3(4, DIMC / 48, BATCH), 256, 0, stream>>>(
      s2, mask_buf, s4);
  // stage 2: 56 -> 112
  comp_conv_kernel<56><<<dim3(13, 2, BATCH), 256, 0, stream>>>(
      s4, g56, cwT + 2 * (CINC * COMPC), cb[2], comp_buf);
  enc_mask_kernel<56><<<dim3(7, 4, BATCH), 256, 0, stream>>>(
      comp_buf, ewT2 + 2 * (size_t)EW2_PER_S, eb[2], mask_buf);
  carafe_kernel<56><<<dim3(13, DIMC / 48, BATCH), 256, 0, stream>>>(
      s4, mask_buf, s8);
  // stage 3: 112 -> 224
  comp_conv_kernel<112><<<dim3(49, 2, BATCH), 256, 0, stream>>>(
      s8, g112, cwT + 3 * (CINC * COMPC), cb[3], comp_buf);
  enc_mask_kernel<112><<<dim3(25, 4, BATCH), 256, 0, stream>>>(
      comp_buf, ewT2 + 3 * (size_t)EW2_PER_S, eb[3], mask_buf);
  carafe_kernel<112><<<dim3(49, DIMC / 48, BATCH), 256, 0, stream>>>(
      s8, mask_buf, out);

  final_conv_mfma3<<<dim3((GSZ * GSZ) / 64, BATCH), 512, 0, stream>>>(
      guidance, Whi, Wlo, pb, out);
}